// Round 1
// baseline (439.031 us; speedup 1.0000x reference)
//
#include <hip/hip_runtime.h>
#include <hip/hip_bf16.h>

// Problem constants (from reference): B=1, N_PATCH=N_TOK=512, D_MODEL=1024,
// HEADS=8 (dh=128), WINDOW=64 -> L=66 slots per query row.
#define MDIM 512      // rows (tokens/patches)
#define NDIM 1024     // d_model
#define LSLOT 66
#define BM 64
#define BN 64
#define BK 16

struct GDesc {
    const float* A;     // (512, K) row-major
    const float* W;     // (1024, K) row-major  (computes A @ W^T)
    const float* bias;  // (1024)
    const float* res;   // optional residual (512,1024) or nullptr
    float* C;           // (512,1024)
    int K;
};
struct GBatch { GDesc d[6]; };

__global__ __launch_bounds__(256) void gemm_batch(GBatch gb) {
    GDesc g = gb.d[blockIdx.z];
    __shared__ float As[BK][BM + 1];
    __shared__ float Ws[BK][BN + 1];
    const int tid = threadIdx.x;
    const int m0 = blockIdx.y * BM;
    const int n0 = blockIdx.x * BN;
    const int tx = tid & 15;        // 0..15 -> n
    const int ty = tid >> 4;        // 0..15 -> m
    const int lr = tid >> 2;        // 0..63 row within tile
    const int lc = (tid & 3) * 4;   // 0,4,8,12 k-offset
    const int K = g.K;

    float acc[4][4];
#pragma unroll
    for (int i = 0; i < 4; ++i)
#pragma unroll
        for (int j = 0; j < 4; ++j) acc[i][j] = 0.f;

    for (int kt = 0; kt < K; kt += BK) {
        const float4 a4 = *(const float4*)(g.A + (size_t)(m0 + lr) * K + kt + lc);
        const float4 w4 = *(const float4*)(g.W + (size_t)(n0 + lr) * K + kt + lc);
        As[lc + 0][lr] = a4.x; As[lc + 1][lr] = a4.y;
        As[lc + 2][lr] = a4.z; As[lc + 3][lr] = a4.w;
        Ws[lc + 0][lr] = w4.x; Ws[lc + 1][lr] = w4.y;
        Ws[lc + 2][lr] = w4.z; Ws[lc + 3][lr] = w4.w;
        __syncthreads();
#pragma unroll
        for (int k = 0; k < BK; ++k) {
            float av[4], wv[4];
#pragma unroll
            for (int i = 0; i < 4; ++i) av[i] = As[k][ty * 4 + i];
#pragma unroll
            for (int j = 0; j < 4; ++j) wv[j] = Ws[k][tx * 4 + j];
#pragma unroll
            for (int i = 0; i < 4; ++i)
#pragma unroll
                for (int j = 0; j < 4; ++j) acc[i][j] += av[i] * wv[j];
        }
        __syncthreads();
    }

    // Epilogue: bias (+ residual), vectorized store
#pragma unroll
    for (int i = 0; i < 4; ++i) {
        const int m = m0 + ty * 4 + i;
        const int n = n0 + tx * 4;
        float4 v;
        v.x = acc[i][0] + g.bias[n + 0];
        v.y = acc[i][1] + g.bias[n + 1];
        v.z = acc[i][2] + g.bias[n + 2];
        v.w = acc[i][3] + g.bias[n + 3];
        if (g.res) {
            const float4 r = *(const float4*)(g.res + (size_t)m * NDIM + n);
            v.x += r.x; v.y += r.y; v.z += r.z; v.w += r.w;
        }
        *(float4*)(g.C + (size_t)m * NDIM + n) = v;
    }
}

struct AttnArgs {
    const float *Q, *K, *V, *kb, *vb;
    float* O;
};

// One block per (query row n, which attention). 256 threads.
__global__ __launch_bounds__(256) void attn_kernel(AttnArgs a0, AttnArgs a1) {
    AttnArgs a = blockIdx.y ? a1 : a0;
    const int n = blockIdx.x;
    const int tid = threadIdx.x;

    __shared__ float qs[NDIM];
    __shared__ float sl[8][LSLOT];
    __shared__ float inv_sum[8];

    ((float4*)qs)[tid] = ((const float4*)(a.Q + (size_t)n * NDIM))[tid];

    // window geometry (exact reproduction of reference mask semantics)
    const int lo_inv = max(0, 32 - n);          // leading invalid slots
    const int hi_inv = max(0, n - 478);         // trailing invalid slots
    const int length = LSLOT - lo_inv - hi_inv; // real context tokens
    const int n_zero = max(0, 64 - length);     // zero-pad slots that attend
    __syncthreads();

    const float scale = 0.088388347648318447f;  // 1/sqrt(128)

    // Phase 1: scores s[h][l]
    for (int task = tid; task < 8 * LSLOT; task += 256) {
        const int h = task / LSLOT;
        const int l = task % LSLOT;
        const int idxn = n - 32 + l;
        const bool valid = (idxn >= 0) && (idxn < MDIM);
        bool attend = valid;
        if (!valid) {
            const int inv_rank = (l < lo_inv) ? l : (l - (LSLOT - hi_inv));
            attend = inv_rank < n_zero;
        }
        float sv = -1e30f;
        if (attend) {
            const float4* kr = (const float4*)(valid ? (a.K + (size_t)idxn * NDIM + h * 128)
                                                     : (a.kb + h * 128));
            const float4* qr = (const float4*)(qs + h * 128);
            float dot = 0.f;
#pragma unroll
            for (int d = 0; d < 32; ++d) {
                const float4 kk = kr[d], qq = qr[d];
                dot += kk.x * qq.x + kk.y * qq.y + kk.z * qq.z + kk.w * qq.w;
            }
            sv = dot * scale;
        }
        sl[h][l] = sv;
    }
    __syncthreads();

    // Phase 2: softmax per head (store unnormalized exp + inv sum)
    if (tid < 8) {
        const int h = tid;
        float m = -1e30f;
        for (int l = 0; l < LSLOT; ++l) m = fmaxf(m, sl[h][l]);
        float s = 0.f;
        for (int l = 0; l < LSLOT; ++l) {
            const float e = expf(sl[h][l] - m);
            sl[h][l] = e;
            s += e;
        }
        inv_sum[h] = 1.0f / s;
    }
    __syncthreads();

    // Phase 3: O[n] = (sum_l p[l] * V[idx(l)]) * inv_sum
    const int d0 = tid * 4;
    const int h = tid >> 5;  // d0 / 128
    float4 acc = {0.f, 0.f, 0.f, 0.f};
    for (int l = 0; l < LSLOT; ++l) {
        const float w = sl[h][l];
        if (w != 0.f) {
            const int idxn = n - 32 + l;
            const bool valid = (idxn >= 0) && (idxn < MDIM);
            const float4 vv = *(const float4*)((valid ? (a.V + (size_t)idxn * NDIM) : a.vb) + d0);
            acc.x += w * vv.x; acc.y += w * vv.y; acc.z += w * vv.z; acc.w += w * vv.w;
        }
    }
    const float is = inv_sum[h];
    acc.x *= is; acc.y *= is; acc.z *= is; acc.w *= is;
    *(float4*)(a.O + (size_t)n * NDIM + d0) = acc;
}

extern "C" void kernel_launch(void* const* d_in, const int* in_sizes, int n_in,
                              void* d_out, int out_size, void* d_ws, size_t ws_size,
                              hipStream_t stream) {
    const float* images = (const float*)d_in[0];   // (512,1024)
    const float* caps   = (const float*)d_in[1];   // (512,768)
    // d_in[2] = text_input_ids (unused)
    const float* tp_w = (const float*)d_in[3];
    const float* tp_b = (const float*)d_in[4];
    const float* ip_w = (const float*)d_in[5];
    const float* ip_b = (const float*)d_in[6];
    const float* ia_qw = (const float*)d_in[7];  const float* ia_qb = (const float*)d_in[8];
    const float* ia_kw = (const float*)d_in[9];  const float* ia_kb = (const float*)d_in[10];
    const float* ia_vw = (const float*)d_in[11]; const float* ia_vb = (const float*)d_in[12];
    const float* ia_ow = (const float*)d_in[13]; const float* ia_ob = (const float*)d_in[14];
    const float* ta_qw = (const float*)d_in[15]; const float* ta_qb = (const float*)d_in[16];
    const float* ta_kw = (const float*)d_in[17]; const float* ta_kb = (const float*)d_in[18];
    const float* ta_vw = (const float*)d_in[19]; const float* ta_vb = (const float*)d_in[20];
    const float* ta_ow = (const float*)d_in[21]; const float* ta_ob = (const float*)d_in[22];

    const size_t S = (size_t)MDIM * NDIM;  // 524288 floats
    float* ws = (float*)d_ws;
    float* txt = ws + 0 * S;
    float* img = ws + 1 * S;
    float* Qi  = ws + 2 * S;
    float* Ki  = ws + 3 * S;
    float* Vi  = ws + 4 * S;
    float* Qt  = ws + 5 * S;
    float* Kt  = ws + 6 * S;
    float* Vt  = ws + 7 * S;
    float* Oi  = ws + 8 * S;
    float* Ot  = ws + 9 * S;

    float* fused_img = (float*)d_out;
    float* fused_txt = (float*)d_out + S;

    dim3 blk(256);
    dim3 tiles(NDIM / BN, MDIM / BM);  // 16 x 8

    // Stage 1: input projections txt = caps@tp_w^T+tp_b ; img = images@ip_w^T+ip_b
    GBatch b1 = {};
    b1.d[0] = {caps,   tp_w, tp_b, nullptr, txt, 768};
    b1.d[1] = {images, ip_w, ip_b, nullptr, img, 1024};
    gemm_batch<<<dim3(tiles.x, tiles.y, 2), blk, 0, stream>>>(b1);

    // Stage 2: QKV for both attentions (img-attn: x=img, ctx=txt ; txt-attn: x=txt, ctx=img)
    GBatch b2 = {};
    b2.d[0] = {img, ia_qw, ia_qb, nullptr, Qi, 1024};
    b2.d[1] = {txt, ia_kw, ia_kb, nullptr, Ki, 1024};
    b2.d[2] = {txt, ia_vw, ia_vb, nullptr, Vi, 1024};
    b2.d[3] = {txt, ta_qw, ta_qb, nullptr, Qt, 1024};
    b2.d[4] = {img, ta_kw, ta_kb, nullptr, Kt, 1024};
    b2.d[5] = {img, ta_vw, ta_vb, nullptr, Vt, 1024};
    gemm_batch<<<dim3(tiles.x, tiles.y, 6), blk, 0, stream>>>(b2);

    // Stage 3: sliding-window attention cores
    AttnArgs aa = {Qi, Ki, Vi, ia_kb, ia_vb, Oi};
    AttnArgs ab = {Qt, Kt, Vt, ta_kb, ta_vb, Ot};
    attn_kernel<<<dim3(MDIM, 2), blk, 0, stream>>>(aa, ab);

    // Stage 4: output projections + residual
    GBatch b4 = {};
    b4.d[0] = {Oi, ia_ow, ia_ob, img, fused_img, 1024};
    b4.d[1] = {Ot, ta_ow, ta_ob, txt, fused_txt, 1024};
    gemm_batch<<<dim3(tiles.x, tiles.y, 2), blk, 0, stream>>>(b4);
}

// Round 2
// 260.248 us; speedup vs baseline: 1.6870x; 1.6870x over previous
//
#include <hip/hip_runtime.h>
#include <hip/hip_bf16.h>

// Problem constants: B=1, N_PATCH=N_TOK=512, D_MODEL=1024, HEADS=8 (dh=128),
// WINDOW=64 -> L=66 slots per query row.
#define MDIM 512
#define NDIM 1024
#define LSLOT 66

typedef __attribute__((ext_vector_type(8))) short short8;   // 8 bf16 = 4 VGPR
typedef __attribute__((ext_vector_type(4))) float f32x4;    // MFMA C/D

struct GDesc {
    const float* A;     // (512, K) row-major fp32
    const float* W;     // (1024, K) row-major fp32  (computes A @ W^T)
    const float* bias;  // (1024)
    const float* res;   // optional residual (512,1024) or nullptr
    float* C;           // (512,1024) fp32
    int K;
};
struct GBatch { GDesc d[6]; };

static __device__ __forceinline__ short f2bf(float f) {
    return __builtin_bit_cast(short, __float2bfloat16(f));
}

static __device__ __forceinline__ short8 cvt8(float4 a, float4 b) {
    short8 v;
    v[0] = f2bf(a.x); v[1] = f2bf(a.y); v[2] = f2bf(a.z); v[3] = f2bf(a.w);
    v[4] = f2bf(b.x); v[5] = f2bf(b.y); v[6] = f2bf(b.z); v[7] = f2bf(b.w);
    return v;
}

// bf16-MFMA GEMM, fp32 in/out with in-staging conversion.
// Tile 64x64, BK=32, 4 waves (2x2 of 32x32), LDS double-buffered, 1 barrier/K-step.
// LDS layout: [row][k] bf16, 16B slots XOR-swizzled: slot ^= (row&3)  (T2; makes
// the column-slice ds_read_b128 fragment reads conflict-free).
__global__ __launch_bounds__(256) void gemm_mfma(GBatch gb) {
    GDesc g = gb.d[blockIdx.z];
    const int K = g.K;
    __shared__ __align__(16) short lds[2][2][64 * 32];  // [buf][0=A,1=W]

    const int tid  = threadIdx.x;
    const int lane = tid & 63;
    const int wave = tid >> 6;
    const int wm = (wave >> 1) * 32;   // wave's row offset within tile
    const int wn = (wave & 1) * 32;    // wave's col offset within tile
    const int m0 = blockIdx.y * 64;
    const int n0 = blockIdx.x * 64;

    // staging coords: thread t stages 8 elems of A-tile and 8 of W-tile
    const int srow = tid >> 2;          // 0..63
    const int sk   = (tid & 3) * 8;     // 0,8,16,24
    const int sidx = srow * 32 + ((((sk >> 3) ^ (srow & 3))) << 3);
    const float* gA = g.A + (size_t)(m0 + srow) * K + sk;
    const float* gW = g.W + (size_t)(n0 + srow) * K + sk;

    // fragment coords (mfma_f32_16x16x32_bf16): lane holds row (lane&15),
    // k = (lane>>4)*8 .. +7, read as one ds_read_b128
    const int fr = lane & 15;
    const int fk = (lane >> 4) * 8;     // 0,8,16,24

    f32x4 acc[2][2] = {};
    const int NT = K / 32;

    // prologue: stage K-tile 0 into buf 0
    {
        float4 a0 = *(const float4*)gA, a1 = *(const float4*)(gA + 4);
        float4 w0 = *(const float4*)gW, w1 = *(const float4*)(gW + 4);
        *(short8*)&lds[0][0][sidx] = cvt8(a0, a1);
        *(short8*)&lds[0][1][sidx] = cvt8(w0, w1);
    }
    __syncthreads();

    int buf = 0;
    for (int t = 0; t < NT; ++t) {
        // issue next tile's global loads early (latency hides under MFMA)
        float4 a0, a1, w0, w1;
        const bool more = (t + 1 < NT);
        if (more) {
            const float* pa = gA + (t + 1) * 32;
            const float* pw = gW + (t + 1) * 32;
            a0 = *(const float4*)pa; a1 = *(const float4*)(pa + 4);
            w0 = *(const float4*)pw; w1 = *(const float4*)(pw + 4);
        }

        // fragments + MFMA from lds[buf]
        short8 af[2], wf[2];
#pragma unroll
        for (int i = 0; i < 2; ++i) {
            const int r = wm + i * 16 + fr;
            af[i] = *(short8*)&lds[buf][0][r * 32 + ((((fk >> 3) ^ (r & 3))) << 3)];
            const int c = wn + i * 16 + fr;
            wf[i] = *(short8*)&lds[buf][1][c * 32 + ((((fk >> 3) ^ (c & 3))) << 3)];
        }
#pragma unroll
        for (int i = 0; i < 2; ++i)
#pragma unroll
            for (int j = 0; j < 2; ++j)
                acc[i][j] = __builtin_amdgcn_mfma_f32_16x16x32_bf16(
                    af[i], wf[j], acc[i][j], 0, 0, 0);

        // convert + write next tile into the other buffer
        if (more) {
            *(short8*)&lds[buf ^ 1][0][sidx] = cvt8(a0, a1);
            *(short8*)&lds[buf ^ 1][1][sidx] = cvt8(w0, w1);
        }
        __syncthreads();
        buf ^= 1;
    }

    // epilogue: C/D layout col=lane&15, row=(lane>>4)*4+reg
#pragma unroll
    for (int i = 0; i < 2; ++i) {
#pragma unroll
        for (int j = 0; j < 2; ++j) {
            const int col = n0 + wn + j * 16 + (lane & 15);
            const float b = g.bias[col];
            const int row0 = m0 + wm + i * 16 + (lane >> 4) * 4;
#pragma unroll
            for (int r = 0; r < 4; ++r) {
                float v = acc[i][j][r] + b;
                if (g.res) v += g.res[(size_t)(row0 + r) * NDIM + col];
                g.C[(size_t)(row0 + r) * NDIM + col] = v;
            }
        }
    }
}

struct AttnArgs {
    const float *Q, *K, *V, *kb, *vb;
    float* O;
};

// One block per (query row n, which attention). 256 threads. fp32 core.
__global__ __launch_bounds__(256) void attn_kernel(AttnArgs a0, AttnArgs a1) {
    AttnArgs a = blockIdx.y ? a1 : a0;
    const int n = blockIdx.x;
    const int tid = threadIdx.x;

    __shared__ float qs[NDIM];
    __shared__ float sl[8][LSLOT];
    __shared__ float inv_sum[8];

    ((float4*)qs)[tid] = ((const float4*)(a.Q + (size_t)n * NDIM))[tid];

    // window geometry (exact reproduction of reference mask semantics)
    const int lo_inv = max(0, 32 - n);          // leading invalid slots
    const int hi_inv = max(0, n - 478);         // trailing invalid slots
    const int length = LSLOT - lo_inv - hi_inv; // real context tokens
    const int n_zero = max(0, 64 - length);     // zero-pad slots that attend
    __syncthreads();

    const float scale = 0.088388347648318447f;  // 1/sqrt(128)

    // Phase 1: scores s[h][l]
    for (int task = tid; task < 8 * LSLOT; task += 256) {
        const int h = task / LSLOT;
        const int l = task % LSLOT;
        const int idxn = n - 32 + l;
        const bool valid = (idxn >= 0) && (idxn < MDIM);
        bool attend = valid;
        if (!valid) {
            const int inv_rank = (l < lo_inv) ? l : (l - (LSLOT - hi_inv));
            attend = inv_rank < n_zero;
        }
        float sv = -1e30f;
        if (attend) {
            const float4* kr = (const float4*)(valid ? (a.K + (size_t)idxn * NDIM + h * 128)
                                                     : (a.kb + h * 128));
            const float4* qr = (const float4*)(qs + h * 128);
            float dot = 0.f;
#pragma unroll
            for (int d = 0; d < 32; ++d) {
                const float4 kk = kr[d], qq = qr[d];
                dot += kk.x * qq.x + kk.y * qq.y + kk.z * qq.z + kk.w * qq.w;
            }
            sv = dot * scale;
        }
        sl[h][l] = sv;
    }
    __syncthreads();

    // Phase 2: softmax per head
    if (tid < 8) {
        const int h = tid;
        float m = -1e30f;
        for (int l = 0; l < LSLOT; ++l) m = fmaxf(m, sl[h][l]);
        float s = 0.f;
        for (int l = 0; l < LSLOT; ++l) {
            const float e = expf(sl[h][l] - m);
            sl[h][l] = e;
            s += e;
        }
        inv_sum[h] = 1.0f / s;
    }
    __syncthreads();

    // Phase 3: O[n] = (sum_l p[l] * V[idx(l)]) * inv_sum
    const int d0 = tid * 4;
    const int h = tid >> 5;
    float4 acc = {0.f, 0.f, 0.f, 0.f};
    for (int l = 0; l < LSLOT; ++l) {
        const float w = sl[h][l];
        if (w != 0.f) {
            const int idxn = n - 32 + l;
            const bool valid = (idxn >= 0) && (idxn < MDIM);
            const float4 vv = *(const float4*)((valid ? (a.V + (size_t)idxn * NDIM) : a.vb) + d0);
            acc.x += w * vv.x; acc.y += w * vv.y; acc.z += w * vv.z; acc.w += w * vv.w;
        }
    }
    const float is = inv_sum[h];
    acc.x *= is; acc.y *= is; acc.z *= is; acc.w *= is;
    *(float4*)(a.O + (size_t)n * NDIM + d0) = acc;
}

extern "C" void kernel_launch(void* const* d_in, const int* in_sizes, int n_in,
                              void* d_out, int out_size, void* d_ws, size_t ws_size,
                              hipStream_t stream) {
    const float* images = (const float*)d_in[0];   // (512,1024)
    const float* caps   = (const float*)d_in[1];   // (512,768)
    // d_in[2] = text_input_ids (unused)
    const float* tp_w = (const float*)d_in[3];
    const float* tp_b = (const float*)d_in[4];
    const float* ip_w = (const float*)d_in[5];
    const float* ip_b = (const float*)d_in[6];
    const float* ia_qw = (const float*)d_in[7];  const float* ia_qb = (const float*)d_in[8];
    const float* ia_kw = (const float*)d_in[9];  const float* ia_kb = (const float*)d_in[10];
    const float* ia_vw = (const float*)d_in[11]; const float* ia_vb = (const float*)d_in[12];
    const float* ia_ow = (const float*)d_in[13]; const float* ia_ob = (const float*)d_in[14];
    const float* ta_qw = (const float*)d_in[15]; const float* ta_qb = (const float*)d_in[16];
    const float* ta_kw = (const float*)d_in[17]; const float* ta_kb = (const float*)d_in[18];
    const float* ta_vw = (const float*)d_in[19]; const float* ta_vb = (const float*)d_in[20];
    const float* ta_ow = (const float*)d_in[21]; const float* ta_ob = (const float*)d_in[22];

    const size_t S = (size_t)MDIM * NDIM;  // 524288 floats
    float* ws = (float*)d_ws;
    float* txt = ws + 0 * S;
    float* img = ws + 1 * S;
    float* Qi  = ws + 2 * S;
    float* Ki  = ws + 3 * S;
    float* Vi  = ws + 4 * S;
    float* Qt  = ws + 5 * S;
    float* Kt  = ws + 6 * S;
    float* Vt  = ws + 7 * S;
    float* Oi  = ws + 8 * S;
    float* Ot  = ws + 9 * S;

    float* fused_img = (float*)d_out;
    float* fused_txt = (float*)d_out + S;

    dim3 blk(256);
    dim3 tiles(NDIM / 64, MDIM / 64);  // 16 x 8 = 128 blocks per GEMM

    // Stage 1: input projections
    GBatch b1 = {};
    b1.d[0] = {caps,   tp_w, tp_b, nullptr, txt, 768};
    b1.d[1] = {images, ip_w, ip_b, nullptr, img, 1024};
    gemm_mfma<<<dim3(tiles.x, tiles.y, 2), blk, 0, stream>>>(b1);

    // Stage 2: QKV for both attentions
    GBatch b2 = {};
    b2.d[0] = {img, ia_qw, ia_qb, nullptr, Qi, 1024};
    b2.d[1] = {txt, ia_kw, ia_kb, nullptr, Ki, 1024};
    b2.d[2] = {txt, ia_vw, ia_vb, nullptr, Vi, 1024};
    b2.d[3] = {txt, ta_qw, ta_qb, nullptr, Qt, 1024};
    b2.d[4] = {img, ta_kw, ta_kb, nullptr, Kt, 1024};
    b2.d[5] = {img, ta_vw, ta_vb, nullptr, Vt, 1024};
    gemm_mfma<<<dim3(tiles.x, tiles.y, 6), blk, 0, stream>>>(b2);

    // Stage 3: sliding-window attention cores
    AttnArgs aa = {Qi, Ki, Vi, ia_kb, ia_vb, Oi};
    AttnArgs ab = {Qt, Kt, Vt, ta_kb, ta_vb, Ot};
    attn_kernel<<<dim3(MDIM, 2), blk, 0, stream>>>(aa, ab);

    // Stage 4: output projections + residual
    GBatch b4 = {};
    b4.d[0] = {Oi, ia_ow, ia_ob, img, fused_img, 1024};
    b4.d[1] = {Ot, ta_ow, ta_ob, txt, fused_txt, 1024};
    gemm_mfma<<<dim3(tiles.x, tiles.y, 2), blk, 0, stream>>>(b4);
}

// Round 3
// 209.635 us; speedup vs baseline: 2.0943x; 1.2414x over previous
//
#include <hip/hip_runtime.h>
#include <hip/hip_bf16.h>

// B=1, N_PATCH=N_TOK=512, D_MODEL=1024, HEADS=8 (dh=128), WINDOW=64 -> L=66.
#define MDIM 512
#define NDIM 1024
#define LSLOT 66

typedef __attribute__((ext_vector_type(8))) short short8;   // 8 bf16 = 4 VGPR
typedef __attribute__((ext_vector_type(4))) float f32x4;    // MFMA C/D

struct GDesc {
    const float* A;     // (512, K) row-major fp32
    const float* W;     // (1024, K) row-major fp32  (computes A @ W^T)
    const float* bias;  // (1024)
    const float* res;   // optional residual (512,1024) or nullptr
    float* C;           // (512,1024) fp32
    int K;
};
struct GBatch { GDesc d[6]; };

static __device__ __forceinline__ short f2bf(float f) {
    return __builtin_bit_cast(short, __float2bfloat16(f));
}
static __device__ __forceinline__ short8 cvt8(float4 a, float4 b) {
    short8 v;
    v[0] = f2bf(a.x); v[1] = f2bf(a.y); v[2] = f2bf(a.z); v[3] = f2bf(a.w);
    v[4] = f2bf(b.x); v[5] = f2bf(b.y); v[6] = f2bf(b.z); v[7] = f2bf(b.w);
    return v;
}

// bf16-MFMA GEMM, fp32 in/out. Tile 64x64, BK=64, 4 waves (2x2 of 32x32),
// LDS double-buffered (32 KB), 1 barrier/K-step.
// LDS element (row,k) at row*64 + ((k>>3) ^ (row&7))*8 + (k&7)  [8-slot XOR swizzle,
// balanced banks for both the staging writes and the fragment column-slice reads].
__global__ __launch_bounds__(256) void gemm_mfma(GBatch gb) {
    GDesc g = gb.d[blockIdx.z];
    const int K = g.K;
    __shared__ __align__(16) short lds[2][2][64 * 64];  // [buf][0=A,1=W]

    const int tid  = threadIdx.x;
    const int lane = tid & 63;
    const int wave = tid >> 6;
    const int wm = (wave >> 1) * 32;
    const int wn = (wave & 1) * 32;
    const int m0 = blockIdx.y * 64;
    const int n0 = blockIdx.x * 64;

    // staging: thread t covers row=t>>2, k=[sk, sk+16)
    const int srow = tid >> 2;
    const int sk   = (tid & 3) * 16;
    const int e0 = (sk >> 3);                 // even chunk index
    const int sidx0 = srow * 64 + ((e0 ^ (srow & 7)) << 3);
    const int sidx1 = srow * 64 + (((e0 + 1) ^ (srow & 7)) << 3);
    const float* gA = g.A + (size_t)(m0 + srow) * K + sk;
    const float* gW = g.W + (size_t)(n0 + srow) * K + sk;

    // fragment coords (mfma_f32_16x16x32_bf16): row r=base+(lane&15), chunk kk*4+(lane>>4)
    const int fr = lane & 15;
    const int fq = lane >> 4;      // 0..3

    f32x4 acc[2][2] = {};
    const int NT = K / 64;

    // prologue: stage K-tile 0 into buf 0
    {
        float4 a0 = *(const float4*)gA,       a1 = *(const float4*)(gA + 4);
        float4 a2 = *(const float4*)(gA + 8), a3 = *(const float4*)(gA + 12);
        float4 w0 = *(const float4*)gW,       w1 = *(const float4*)(gW + 4);
        float4 w2 = *(const float4*)(gW + 8), w3 = *(const float4*)(gW + 12);
        *(short8*)&lds[0][0][sidx0] = cvt8(a0, a1);
        *(short8*)&lds[0][0][sidx1] = cvt8(a2, a3);
        *(short8*)&lds[0][1][sidx0] = cvt8(w0, w1);
        *(short8*)&lds[0][1][sidx1] = cvt8(w2, w3);
    }
    __syncthreads();

    int buf = 0;
    for (int t = 0; t < NT; ++t) {
        float4 a0, a1, a2, a3, w0, w1, w2, w3;
        const bool more = (t + 1 < NT);
        if (more) {
            const float* pa = gA + (t + 1) * 64;
            const float* pw = gW + (t + 1) * 64;
            a0 = *(const float4*)pa;       a1 = *(const float4*)(pa + 4);
            a2 = *(const float4*)(pa + 8); a3 = *(const float4*)(pa + 12);
            w0 = *(const float4*)pw;       w1 = *(const float4*)(pw + 4);
            w2 = *(const float4*)(pw + 8); w3 = *(const float4*)(pw + 12);
        }

        short8 af[2][2], wf[2][2];
#pragma unroll
        for (int i = 0; i < 2; ++i) {
            const int r = wm + i * 16 + fr;
            const int c = wn + i * 16 + fr;
#pragma unroll
            for (int kk = 0; kk < 2; ++kk) {
                const int sa = ((kk * 4 + fq) ^ (fr & 7)) << 3;
                af[i][kk] = *(short8*)&lds[buf][0][r * 64 + sa];
                wf[i][kk] = *(short8*)&lds[buf][1][c * 64 + sa];
            }
        }
#pragma unroll
        for (int kk = 0; kk < 2; ++kk)
#pragma unroll
            for (int i = 0; i < 2; ++i)
#pragma unroll
                for (int j = 0; j < 2; ++j)
                    acc[i][j] = __builtin_amdgcn_mfma_f32_16x16x32_bf16(
                        af[i][kk], wf[j][kk], acc[i][j], 0, 0, 0);

        if (more) {
            *(short8*)&lds[buf ^ 1][0][sidx0] = cvt8(a0, a1);
            *(short8*)&lds[buf ^ 1][0][sidx1] = cvt8(a2, a3);
            *(short8*)&lds[buf ^ 1][1][sidx0] = cvt8(w0, w1);
            *(short8*)&lds[buf ^ 1][1][sidx1] = cvt8(w2, w3);
        }
        __syncthreads();
        buf ^= 1;
    }

    // epilogue: C/D layout col=lane&15, row=(lane>>4)*4+reg
#pragma unroll
    for (int i = 0; i < 2; ++i) {
#pragma unroll
        for (int j = 0; j < 2; ++j) {
            const int col = n0 + wn + j * 16 + (lane & 15);
            const float b = g.bias[col];
            const int row0 = m0 + wm + i * 16 + (lane >> 4) * 4;
#pragma unroll
            for (int r = 0; r < 4; ++r) {
                float v = acc[i][j][r] + b;
                if (g.res) v += g.res[(size_t)(row0 + r) * NDIM + col];
                g.C[(size_t)(row0 + r) * NDIM + col] = v;
            }
        }
    }
}

struct AttnArgs {
    const float *Q, *K, *V, *kb, *vb;
    float* O;
};

// Tiled sliding-window attention: block = (32 query rows) x (1 head) x (1 attn).
// Grid (16, 8, 2) = 256 blocks. 256 threads. K/V window (97 rows x 128) staged in
// LDS fp32 with float4-slot XOR swizzle; OOB rows staged as kb/vb (zero-pad slots).
__global__ __launch_bounds__(256) void attn_tile(AttnArgs a0, AttnArgs a1) {
    const AttnArgs a = blockIdx.z ? a1 : a0;
    const int h  = blockIdx.y;
    const int n0 = blockIdx.x * 32;
    const int tid = threadIdx.x;

    __shared__ float Ks[97 * 128];
    __shared__ float Vs[97 * 128];
    __shared__ float Qs[32 * 132];
    __shared__ float Ps[32 * 68];
    __shared__ float InvS[32];

    // stage K/V window rows wp=0..96 (ctx rows n0-32 .. n0+64); OOB -> kb/vb
    for (int i = tid; i < 97 * 32; i += 256) {
        const int wp = i >> 5, d4 = i & 31;
        const int idx = n0 - 32 + wp;
        const bool valid = (idx >= 0) && (idx < MDIM);
        const float* sk = (valid ? (a.K + (size_t)idx * NDIM) : a.kb) + h * 128;
        const float* sv = (valid ? (a.V + (size_t)idx * NDIM) : a.vb) + h * 128;
        const float4 kv = *(const float4*)(sk + d4 * 4);
        const float4 vv = *(const float4*)(sv + d4 * 4);
        const int slot = d4 ^ (wp & 31);
        *(float4*)&Ks[wp * 128 + slot * 4] = kv;
        *(float4*)&Vs[wp * 128 + slot * 4] = vv;
    }
    // stage Q tile (stride 132 floats to break row-bank alignment)
    for (int i = tid; i < 32 * 32; i += 256) {
        const int r = i >> 5, d4 = i & 31;
        *(float4*)&Qs[r * 132 + d4 * 4] =
            *(const float4*)(a.Q + (size_t)(n0 + r) * NDIM + h * 128 + d4 * 4);
    }
    __syncthreads();

    const int r = tid >> 3, sub = tid & 7;   // 8 lanes per query row, same wave
    const int n = n0 + r;
    const int lo_inv = max(0, 32 - n);
    const int hi_inv = max(0, n - 478);
    const int n_zero = max(0, 64 - (LSLOT - lo_inv - hi_inv));
    const float scale = 0.088388347648318447f;  // 1/sqrt(128)

    // phase 1: scores. thread (r,sub) does full dots for l = sub+8k (k=0..8).
    float dots[9];
#pragma unroll
    for (int k = 0; k < 9; ++k) dots[k] = 0.f;
#pragma unroll
    for (int db = 0; db < 4; ++db) {       // 4 blocks of 8 float4 along d
        float4 q[8];
#pragma unroll
        for (int c = 0; c < 8; ++c) q[c] = *(float4*)&Qs[r * 132 + (db * 8 + c) * 4];
        for (int k = 0; k < 9; ++k) {
            const int l = sub + 8 * k;
            if (l >= LSLOT) break;
            const int wp = r + l, key = wp & 31;
            float accd = dots[k];
#pragma unroll
            for (int c = 0; c < 8; ++c) {
                const int d4 = db * 8 + c;
                const float4 kv = *(float4*)&Ks[wp * 128 + (d4 ^ key) * 4];
                accd += kv.x * q[c].x + kv.y * q[c].y + kv.z * q[c].z + kv.w * q[c].w;
            }
            dots[k] = accd;
        }
    }
    for (int k = 0; k < 9; ++k) {
        const int l = sub + 8 * k;
        if (l >= LSLOT) break;
        const int idx = n - 32 + l;
        const bool valid = (idx >= 0) && (idx < MDIM);
        bool attend = valid;
        if (!valid) {
            const int ir = (l < lo_inv) ? l : (l - (LSLOT - hi_inv));
            attend = ir < n_zero;
        }
        Ps[r * 68 + l] = attend ? dots[k] * scale : -1e30f;
    }
    __syncthreads();

    // phase 2: softmax, 8 lanes per row, shfl_xor width-8 reduce
    {
        float m = -1e30f;
        for (int k = 0; k < 9; ++k) {
            const int l = sub + 8 * k;
            if (l < LSLOT) m = fmaxf(m, Ps[r * 68 + l]);
        }
        for (int s = 1; s < 8; s <<= 1) m = fmaxf(m, __shfl_xor(m, s, 64));
        float sum = 0.f;
        for (int k = 0; k < 9; ++k) {
            const int l = sub + 8 * k;
            if (l >= LSLOT) break;
            const float e = expf(Ps[r * 68 + l] - m);
            Ps[r * 68 + l] = e;
            sum += e;
        }
        for (int s = 1; s < 8; s <<= 1) sum += __shfl_xor(sum, s, 64);
        if (sub == 0) InvS[r] = 1.0f / sum;
    }
    __syncthreads();

    // phase 3: PV. thread (r,sub): d4 chunks sub, sub+8, sub+16, sub+24.
    float4 acc[4] = {};
    for (int l = 0; l < LSLOT; ++l) {
        const float p = Ps[r * 68 + l];
        const int wp = r + l, key = wp & 31;
#pragma unroll
        for (int c = 0; c < 4; ++c) {
            const int d4 = sub + 8 * c;
            const float4 vv = *(float4*)&Vs[wp * 128 + (d4 ^ key) * 4];
            acc[c].x += p * vv.x; acc[c].y += p * vv.y;
            acc[c].z += p * vv.z; acc[c].w += p * vv.w;
        }
    }
    const float inv = InvS[r];
#pragma unroll
    for (int c = 0; c < 4; ++c) {
        float4 v = acc[c];
        v.x *= inv; v.y *= inv; v.z *= inv; v.w *= inv;
        *(float4*)(a.O + (size_t)n * NDIM + h * 128 + (sub + 8 * c) * 4) = v;
    }
}

extern "C" void kernel_launch(void* const* d_in, const int* in_sizes, int n_in,
                              void* d_out, int out_size, void* d_ws, size_t ws_size,
                              hipStream_t stream) {
    const float* images = (const float*)d_in[0];
    const float* caps   = (const float*)d_in[1];
    const float* tp_w = (const float*)d_in[3];
    const float* tp_b = (const float*)d_in[4];
    const float* ip_w = (const float*)d_in[5];
    const float* ip_b = (const float*)d_in[6];
    const float* ia_qw = (const float*)d_in[7];  const float* ia_qb = (const float*)d_in[8];
    const float* ia_kw = (const float*)d_in[9];  const float* ia_kb = (const float*)d_in[10];
    const float* ia_vw = (const float*)d_in[11]; const float* ia_vb = (const float*)d_in[12];
    const float* ia_ow = (const float*)d_in[13]; const float* ia_ob = (const float*)d_in[14];
    const float* ta_qw = (const float*)d_in[15]; const float* ta_qb = (const float*)d_in[16];
    const float* ta_kw = (const float*)d_in[17]; const float* ta_kb = (const float*)d_in[18];
    const float* ta_vw = (const float*)d_in[19]; const float* ta_vb = (const float*)d_in[20];
    const float* ta_ow = (const float*)d_in[21]; const float* ta_ob = (const float*)d_in[22];

    const size_t S = (size_t)MDIM * NDIM;
    float* ws = (float*)d_ws;
    float* txt = ws + 0 * S;
    float* img = ws + 1 * S;
    float* Qi  = ws + 2 * S;
    float* Ki  = ws + 3 * S;
    float* Vi  = ws + 4 * S;
    float* Qt  = ws + 5 * S;
    float* Kt  = ws + 6 * S;
    float* Vt  = ws + 7 * S;
    float* Oi  = ws + 8 * S;
    float* Ot  = ws + 9 * S;

    float* fused_img = (float*)d_out;
    float* fused_txt = (float*)d_out + S;

    dim3 blk(256);
    dim3 tiles(NDIM / 64, MDIM / 64);  // 16 x 8

    GBatch b1 = {};
    b1.d[0] = {caps,   tp_w, tp_b, nullptr, txt, 768};
    b1.d[1] = {images, ip_w, ip_b, nullptr, img, 1024};
    gemm_mfma<<<dim3(tiles.x, tiles.y, 2), blk, 0, stream>>>(b1);

    GBatch b2 = {};
    b2.d[0] = {img, ia_qw, ia_qb, nullptr, Qi, 1024};
    b2.d[1] = {txt, ia_kw, ia_kb, nullptr, Ki, 1024};
    b2.d[2] = {txt, ia_vw, ia_vb, nullptr, Vi, 1024};
    b2.d[3] = {txt, ta_qw, ta_qb, nullptr, Qt, 1024};
    b2.d[4] = {img, ta_kw, ta_kb, nullptr, Kt, 1024};
    b2.d[5] = {img, ta_vw, ta_vb, nullptr, Vt, 1024};
    gemm_mfma<<<dim3(tiles.x, tiles.y, 6), blk, 0, stream>>>(b2);

    AttnArgs aa = {Qi, Ki, Vi, ia_kb, ia_vb, Oi};
    AttnArgs ab = {Qt, Kt, Vt, ta_kb, ta_vb, Ot};
    attn_tile<<<dim3(16, 8, 2), blk, 0, stream>>>(aa, ab);

    GBatch b4 = {};
    b4.d[0] = {Oi, ia_ow, ia_ob, img, fused_img, 1024};
    b4.d[1] = {Ot, ta_ow, ta_ob, txt, fused_txt, 1024};
    gemm_mfma<<<dim3(tiles.x, tiles.y, 2), blk, 0, stream>>>(b4);
}

// Round 4
// 186.836 us; speedup vs baseline: 2.3498x; 1.1220x over previous
//
#include <hip/hip_runtime.h>
#include <hip/hip_bf16.h>

// B=1, N_PATCH=N_TOK=512, D_MODEL=1024, HEADS=8 (dh=128), WINDOW=64 -> L=66.
#define MDIM 512
#define NDIM 1024
#define LSLOT 66

typedef __attribute__((ext_vector_type(8))) short short8;   // 8 bf16 = 4 VGPR
typedef __attribute__((ext_vector_type(4))) short short4v;  // 4 bf16 = 8 B
typedef __attribute__((ext_vector_type(4))) float f32x4;    // MFMA C/D
typedef __hip_bfloat16 bf16;

static __device__ __forceinline__ short f2bf(float f) {
    return __builtin_bit_cast(short, __float2bfloat16(f));
}
static __device__ __forceinline__ short8 cvt8(float4 a, float4 b) {
    short8 v;
    v[0] = f2bf(a.x); v[1] = f2bf(a.y); v[2] = f2bf(a.z); v[3] = f2bf(a.w);
    v[4] = f2bf(b.x); v[5] = f2bf(b.y); v[6] = f2bf(b.z); v[7] = f2bf(b.w);
    return v;
}

// async 16B global -> LDS (DMA, no VGPR round-trip). LDS dest = uniform base + lane*16.
static __device__ __forceinline__ void gload16(const void* g, void* l) {
    __builtin_amdgcn_global_load_lds(
        (const __attribute__((address_space(1))) unsigned int*)g,
        (__attribute__((address_space(3))) unsigned int*)l, 16, 0, 0);
}

// ---------------- prep: fp32 -> bf16 conversions ----------------
struct CvtDesc { const float* src; bf16* dst; int n; };
struct CvtBatch { CvtDesc d[12]; };

__global__ __launch_bounds__(256) void cvt_bf16(CvtBatch cb) {
    CvtDesc c = cb.d[blockIdx.z];
    const int i = (blockIdx.x * 256 + threadIdx.x) * 8;
    if (i >= c.n) return;
    const float4 a = *(const float4*)(c.src + i);
    const float4 b = *(const float4*)(c.src + i + 4);
    *(short8*)((short*)c.dst + i) = cvt8(a, b);
}

// ---------------- bf16 MFMA GEMM (m97-style) ----------------
// C = A @ W^T + bias (+res). A:(512,K) bf16, W:(Ntot,K) bf16, C fp32 (+optional bf16 copy).
// Tile 64x64, BK=64, 2 waves; wave w computes rows [w*32, w*32+32) x all 64 cols
// (2x4 fragments -> 16 MFMA : 12 ds_read_b128 per K-step). Double-buffered LDS,
// 1 barrier/K-step. Staging via global_load_lds w/ pre-swizzled per-lane source:
// LDS chunk s of row r holds global k-chunk (s ^ (r&7))  [both-sides XOR swizzle].
struct GDesc {
    const bf16* A;      // (512, K)
    const bf16* W;      // (1024, K)
    const float* bias;  // (1024)
    const float* res;   // optional fp32 residual or nullptr
    float* C;           // fp32 out (512,1024)
    bf16* Cb;           // optional bf16 dual-out or nullptr
    int K;              // 768 or 1024 (multiple of 64)
};
struct GBatch { GDesc d[6]; };

__global__ __launch_bounds__(128) void gemm_bf16(GBatch gb) {
    GDesc g = gb.d[blockIdx.z];
    const int K = g.K;
    __shared__ __align__(16) short lds[2][2][64 * 64];  // [dbuf][0=A,1=W] 32 KB

    const int tid  = threadIdx.x;
    const int lane = tid & 63;
    const int wave = tid >> 6;          // wave0 stages A-tile, wave1 stages W-tile
    const int m0 = blockIdx.y * 64;
    const int n0 = blockIdx.x * 64;
    const int wm = wave * 32;

    // staging source: lane l fetches (row = i*8 + (l>>3), kchunk = (l&7)^(l>>3))
    const size_t rowb = (size_t)K * 2;  // row stride in bytes
    const char* sbase = (const char*)(wave ? (const void*)g.W : (const void*)g.A)
                      + (size_t)(wave ? n0 : m0) * rowb
                      + (size_t)(lane >> 3) * rowb
                      + (size_t)(((lane & 7) ^ (lane >> 3)) << 4);

    const int fr = lane & 15;
    const int fq = lane >> 4;           // 0..3

    f32x4 acc[2][4] = {};
    const int NT = K / 64;

    // prologue: stage K-tile 0 into buf 0
#pragma unroll
    for (int i = 0; i < 8; ++i)
        gload16(sbase + (size_t)i * 8 * rowb, &lds[0][wave][i * 512]);
    __syncthreads();

    int buf = 0;
    for (int t = 0; t < NT; ++t) {
        if (t + 1 < NT) {   // async-stage next tile into other buffer
            const char* p = sbase + (size_t)(t + 1) * 128;
#pragma unroll
            for (int i = 0; i < 8; ++i)
                gload16(p + (size_t)i * 8 * rowb, &lds[buf ^ 1][wave][i * 512]);
        }

        short8 af[2][2], wf[4][2];
#pragma unroll
        for (int kk = 0; kk < 2; ++kk) {
            const int ch = kk * 4 + fq;
#pragma unroll
            for (int i = 0; i < 2; ++i) {
                const int r = wm + i * 16 + fr;
                af[i][kk] = *(const short8*)&lds[buf][0][r * 64 + ((ch ^ (r & 7)) << 3)];
            }
#pragma unroll
            for (int j = 0; j < 4; ++j) {
                const int c = j * 16 + fr;
                wf[j][kk] = *(const short8*)&lds[buf][1][c * 64 + ((ch ^ (c & 7)) << 3)];
            }
        }
#pragma unroll
        for (int kk = 0; kk < 2; ++kk)
#pragma unroll
            for (int i = 0; i < 2; ++i)
#pragma unroll
                for (int j = 0; j < 4; ++j)
                    acc[i][j] = __builtin_amdgcn_mfma_f32_16x16x32_bf16(
                        af[i][kk], wf[j][kk], acc[i][j], 0, 0, 0);

        __syncthreads();   // drains vmcnt(0): next tile resident; buf safe to reuse
        buf ^= 1;
    }

    // epilogue: C/D layout col=lane&15, row=(lane>>4)*4+reg
#pragma unroll
    for (int i = 0; i < 2; ++i) {
        const int row0 = m0 + wm + i * 16 + fq * 4;
#pragma unroll
        for (int j = 0; j < 4; ++j) {
            const int col = n0 + j * 16 + fr;
            const float b = g.bias[col];
#pragma unroll
            for (int r = 0; r < 4; ++r) {
                float v = acc[i][j][r] + b;
                const size_t o = (size_t)(row0 + r) * NDIM + col;
                if (g.res) v += g.res[o];
                g.C[o] = v;
                if (g.Cb) g.Cb[o] = __float2bfloat16(v);
            }
        }
    }
}

// ---------------- sliding-window attention ----------------
struct AttnArgs {
    const float *Q, *K, *V, *kb, *vb;
    bf16* O;   // bf16 out -> feeds stage-4 GEMM A directly
};

// block = (32 query rows) x (1 head) x (1 attn); grid (16,8,2), 256 threads.
__global__ __launch_bounds__(256) void attn_tile(AttnArgs a0, AttnArgs a1) {
    const AttnArgs a = blockIdx.z ? a1 : a0;
    const int h  = blockIdx.y;
    const int n0 = blockIdx.x * 32;
    const int tid = threadIdx.x;

    __shared__ float Ks[97 * 128];
    __shared__ float Vs[97 * 128];
    __shared__ float Qs[32 * 132];
    __shared__ float Ps[32 * 68];
    __shared__ float InvS[32];

    // stage K/V window rows wp=0..96 (ctx rows n0-32 .. n0+64); OOB -> kb/vb
    for (int i = tid; i < 97 * 32; i += 256) {
        const int wp = i >> 5, d4 = i & 31;
        const int idx = n0 - 32 + wp;
        const bool valid = (idx >= 0) && (idx < MDIM);
        const float* sk = (valid ? (a.K + (size_t)idx * NDIM) : a.kb) + h * 128;
        const float* sv = (valid ? (a.V + (size_t)idx * NDIM) : a.vb) + h * 128;
        const float4 kv = *(const float4*)(sk + d4 * 4);
        const float4 vv = *(const float4*)(sv + d4 * 4);
        const int slot = d4 ^ (wp & 31);
        *(float4*)&Ks[wp * 128 + slot * 4] = kv;
        *(float4*)&Vs[wp * 128 + slot * 4] = vv;
    }
    for (int i = tid; i < 32 * 32; i += 256) {
        const int r = i >> 5, d4 = i & 31;
        *(float4*)&Qs[r * 132 + d4 * 4] =
            *(const float4*)(a.Q + (size_t)(n0 + r) * NDIM + h * 128 + d4 * 4);
    }
    __syncthreads();

    const int r = tid >> 3, sub = tid & 7;
    const int n = n0 + r;
    const int lo_inv = max(0, 32 - n);
    const int hi_inv = max(0, n - 478);
    const int n_zero = max(0, 64 - (LSLOT - lo_inv - hi_inv));
    const float scale = 0.088388347648318447f;  // 1/sqrt(128)

    float dots[9];
#pragma unroll
    for (int k = 0; k < 9; ++k) dots[k] = 0.f;
#pragma unroll
    for (int db = 0; db < 4; ++db) {
        float4 q[8];
#pragma unroll
        for (int c = 0; c < 8; ++c) q[c] = *(float4*)&Qs[r * 132 + (db * 8 + c) * 4];
        for (int k = 0; k < 9; ++k) {
            const int l = sub + 8 * k;
            if (l >= LSLOT) break;
            const int wp = r + l, key = wp & 31;
            float accd = dots[k];
#pragma unroll
            for (int c = 0; c < 8; ++c) {
                const int d4 = db * 8 + c;
                const float4 kv = *(float4*)&Ks[wp * 128 + (d4 ^ key) * 4];
                accd += kv.x * q[c].x + kv.y * q[c].y + kv.z * q[c].z + kv.w * q[c].w;
            }
            dots[k] = accd;
        }
    }
    for (int k = 0; k < 9; ++k) {
        const int l = sub + 8 * k;
        if (l >= LSLOT) break;
        const int idx = n - 32 + l;
        const bool valid = (idx >= 0) && (idx < MDIM);
        bool attend = valid;
        if (!valid) {
            const int ir = (l < lo_inv) ? l : (l - (LSLOT - hi_inv));
            attend = ir < n_zero;
        }
        Ps[r * 68 + l] = attend ? dots[k] * scale : -1e30f;
    }
    __syncthreads();

    {
        float m = -1e30f;
        for (int k = 0; k < 9; ++k) {
            const int l = sub + 8 * k;
            if (l < LSLOT) m = fmaxf(m, Ps[r * 68 + l]);
        }
        for (int s = 1; s < 8; s <<= 1) m = fmaxf(m, __shfl_xor(m, s, 64));
        float sum = 0.f;
        for (int k = 0; k < 9; ++k) {
            const int l = sub + 8 * k;
            if (l >= LSLOT) break;
            const float e = expf(Ps[r * 68 + l] - m);
            Ps[r * 68 + l] = e;
            sum += e;
        }
        for (int s = 1; s < 8; s <<= 1) sum += __shfl_xor(sum, s, 64);
        if (sub == 0) InvS[r] = 1.0f / sum;
    }
    __syncthreads();

    float4 acc[4] = {};
    for (int l = 0; l < LSLOT; ++l) {
        const float p = Ps[r * 68 + l];
        const int wp = r + l, key = wp & 31;
#pragma unroll
        for (int c = 0; c < 4; ++c) {
            const int d4 = sub + 8 * c;
            const float4 vv = *(float4*)&Vs[wp * 128 + (d4 ^ key) * 4];
            acc[c].x += p * vv.x; acc[c].y += p * vv.y;
            acc[c].z += p * vv.z; acc[c].w += p * vv.w;
        }
    }
    const float inv = InvS[r];
#pragma unroll
    for (int c = 0; c < 4; ++c) {
        short4v o;
        o[0] = f2bf(acc[c].x * inv); o[1] = f2bf(acc[c].y * inv);
        o[2] = f2bf(acc[c].z * inv); o[3] = f2bf(acc[c].w * inv);
        *(short4v*)((short*)a.O + (size_t)n * NDIM + h * 128 + (sub + 8 * c) * 4) = o;
    }
}

extern "C" void kernel_launch(void* const* d_in, const int* in_sizes, int n_in,
                              void* d_out, int out_size, void* d_ws, size_t ws_size,
                              hipStream_t stream) {
    const float* images = (const float*)d_in[0];   // (512,1024)
    const float* caps   = (const float*)d_in[1];   // (512,768)
    const float* tp_w = (const float*)d_in[3];
    const float* tp_b = (const float*)d_in[4];
    const float* ip_w = (const float*)d_in[5];
    const float* ip_b = (const float*)d_in[6];
    const float* ia_qw = (const float*)d_in[7];  const float* ia_qb = (const float*)d_in[8];
    const float* ia_kw = (const float*)d_in[9];  const float* ia_kb = (const float*)d_in[10];
    const float* ia_vw = (const float*)d_in[11]; const float* ia_vb = (const float*)d_in[12];
    const float* ia_ow = (const float*)d_in[13]; const float* ia_ob = (const float*)d_in[14];
    const float* ta_qw = (const float*)d_in[15]; const float* ta_qb = (const float*)d_in[16];
    const float* ta_kw = (const float*)d_in[17]; const float* ta_kb = (const float*)d_in[18];
    const float* ta_vw = (const float*)d_in[19]; const float* ta_vb = (const float*)d_in[20];
    const float* ta_ow = (const float*)d_in[21]; const float* ta_ob = (const float*)d_in[22];

    const size_t S = (size_t)MDIM * NDIM;          // 524288
    float* ws = (float*)d_ws;
    // fp32 region (8 buffers)
    float* txt = ws + 0 * S;
    float* img = ws + 1 * S;
    float* Qi  = ws + 2 * S;
    float* Ki  = ws + 3 * S;
    float* Vi  = ws + 4 * S;
    float* Qt  = ws + 5 * S;
    float* Kt  = ws + 6 * S;
    float* Vt  = ws + 7 * S;
    // bf16 region
    bf16* bb     = (bf16*)(ws + 8 * S);
    bf16* capsb  = bb;               // 512*768
    bf16* imgsb  = capsb + 393216;   // 512*1024
    bf16* txtb   = imgsb + S;
    bf16* imgb   = txtb + S;
    bf16* Oib    = imgb + S;
    bf16* Otb    = Oib + S;
    bf16* tp_wb  = Otb + S;          // 1024*768
    bf16* ip_wb  = tp_wb + 786432;
    bf16* qwb[8];
    { bf16* p = ip_wb + 1048576;
      for (int i = 0; i < 8; ++i) { qwb[i] = p; p += 1048576; } }

    float* fused_img = (float*)d_out;
    float* fused_txt = (float*)d_out + S;

    // ---- prep: convert inputs + weights to bf16 ----
    CvtBatch cv = {};
    cv.d[0]  = {caps,   capsb, 393216};
    cv.d[1]  = {images, imgsb, (int)S};
    cv.d[2]  = {tp_w,   tp_wb, 786432};
    cv.d[3]  = {ip_w,   ip_wb, 1048576};
    cv.d[4]  = {ia_qw, qwb[0], 1048576};
    cv.d[5]  = {ia_kw, qwb[1], 1048576};
    cv.d[6]  = {ia_vw, qwb[2], 1048576};
    cv.d[7]  = {ia_ow, qwb[3], 1048576};
    cv.d[8]  = {ta_qw, qwb[4], 1048576};
    cv.d[9]  = {ta_kw, qwb[5], 1048576};
    cv.d[10] = {ta_vw, qwb[6], 1048576};
    cv.d[11] = {ta_ow, qwb[7], 1048576};
    cvt_bf16<<<dim3(512, 1, 12), 256, 0, stream>>>(cv);

    dim3 blk(128);
    dim3 tiles(NDIM / 64, MDIM / 64);  // 16 x 8

    // ---- stage 1: input projections (dual fp32 + bf16 out) ----
    GBatch b1 = {};
    b1.d[0] = {capsb, tp_wb, tp_b, nullptr, txt, txtb, 768};
    b1.d[1] = {imgsb, ip_wb, ip_b, nullptr, img, imgb, 1024};
    gemm_bf16<<<dim3(tiles.x, tiles.y, 2), blk, 0, stream>>>(b1);

    // ---- stage 2: QKV (fp32 out for attn) ----
    GBatch b2 = {};
    b2.d[0] = {imgb, qwb[0], ia_qb, nullptr, Qi, nullptr, 1024};
    b2.d[1] = {txtb, qwb[1], ia_kb, nullptr, Ki, nullptr, 1024};
    b2.d[2] = {txtb, qwb[2], ia_vb, nullptr, Vi, nullptr, 1024};
    b2.d[3] = {txtb, qwb[4], ta_qb, nullptr, Qt, nullptr, 1024};
    b2.d[4] = {imgb, qwb[5], ta_kb, nullptr, Kt, nullptr, 1024};
    b2.d[5] = {imgb, qwb[6], ta_vb, nullptr, Vt, nullptr, 1024};
    gemm_bf16<<<dim3(tiles.x, tiles.y, 6), blk, 0, stream>>>(b2);

    // ---- stage 3: attention (bf16 O out) ----
    AttnArgs aa = {Qi, Ki, Vi, ia_kb, ia_vb, Oib};
    AttnArgs ab = {Qt, Kt, Vt, ta_kb, ta_vb, Otb};
    attn_tile<<<dim3(16, 8, 2), 256, 0, stream>>>(aa, ab);

    // ---- stage 4: output projections + residual ----
    GBatch b4 = {};
    b4.d[0] = {Oib, qwb[3], ia_ob, img, fused_img, nullptr, 1024};
    b4.d[1] = {Otb, qwb[7], ta_ob, txt, fused_txt, nullptr, 1024};
    gemm_bf16<<<dim3(tiles.x, tiles.y, 2), blk, 0, stream>>>(b4);
}

// Round 5
// 179.807 us; speedup vs baseline: 2.4417x; 1.0391x over previous
//
#include <hip/hip_runtime.h>
#include <hip/hip_bf16.h>

// B=1, N_PATCH=N_TOK=512, D_MODEL=1024, HEADS=8 (dh=128), WINDOW=64 -> L=66.
#define MDIM 512
#define NDIM 1024
#define LSLOT 66

typedef __attribute__((ext_vector_type(8))) short short8;   // 8 bf16 = 4 VGPR
typedef __attribute__((ext_vector_type(4))) short short4v;  // 4 bf16 = 8 B
typedef __attribute__((ext_vector_type(4))) float f32x4;    // MFMA C/D
typedef __hip_bfloat16 bf16;

static __device__ __forceinline__ short f2bf(float f) {
    return __builtin_bit_cast(short, __float2bfloat16(f));
}
static __device__ __forceinline__ short8 cvt8(float4 a, float4 b) {
    short8 v;
    v[0] = f2bf(a.x); v[1] = f2bf(a.y); v[2] = f2bf(a.z); v[3] = f2bf(a.w);
    v[4] = f2bf(b.x); v[5] = f2bf(b.y); v[6] = f2bf(b.z); v[7] = f2bf(b.w);
    return v;
}

// async 16B global -> LDS DMA. LDS dest = uniform base + lane*16.
static __device__ __forceinline__ void gload16(const void* g, void* l) {
    __builtin_amdgcn_global_load_lds(
        (const __attribute__((address_space(1))) unsigned int*)g,
        (__attribute__((address_space(3))) unsigned int*)l, 16, 0, 0);
}

// ---------------- prep: fp32 -> bf16 conversions ----------------
struct CvtDesc { const float* src; bf16* dst; int n; };
struct CvtBatch { CvtDesc d[12]; };

__global__ __launch_bounds__(256) void cvt_bf16(CvtBatch cb) {
    CvtDesc c = cb.d[blockIdx.z];
    const int i = (blockIdx.x * 256 + threadIdx.x) * 8;
    if (i >= c.n) return;
    const float4 a = *(const float4*)(c.src + i);
    const float4 b = *(const float4*)(c.src + i + 4);
    *(short8*)((short*)c.dst + i) = cvt8(a, b);
}

// ---------------- bf16 MFMA GEMM, 3-deep counted-vmcnt pipeline ----------------
// C = A @ W^T + bias (+res). Tile 64x64, BK=64, 2 waves (wave w: rows [w*32,w*32+32) x 64 cols).
// 3 LDS buffers (48 KB -> 3 blocks/CU); tile t lives in buf t%3; loads for t+3 are
// issued right after all reads of buf t%3 complete. Main-loop wait is vmcnt(16)
// (2 tiles = 16 loads/wave stay in flight, never drained); tail peels 8 then 0.
// LDS swizzle (both-sides XOR, rule #21): chunk s of row r holds global k-chunk s^(r&7);
// staged with linear LDS dest + inverse-swizzled per-lane global source.
struct GDesc {
    const bf16* A;      // (512, K)
    const bf16* W;      // (1024, K)
    const float* bias;  // (1024)
    const float* res;   // optional fp32 residual or nullptr
    float* C;           // fp32 out (512,1024)
    bf16* Cb;           // optional bf16 dual-out or nullptr
    int K;              // multiple of 64 (768 or 1024 here -> NT 12 or 16)
};
struct GBatch { GDesc d[6]; };

__global__ __launch_bounds__(128) void gemm_bf16(GBatch gb) {
    GDesc g = gb.d[blockIdx.z];
    const int K = g.K;
    __shared__ __align__(16) short lds[3][2][64 * 64];  // [buf][0=A,1=W] 48 KB

    const int tid  = threadIdx.x;
    const int lane = tid & 63;
    const int wave = tid >> 6;          // wave0 stages A-half, wave1 stages W-half
    const int m0 = blockIdx.y * 64;
    const int n0 = blockIdx.x * 64;
    const int wm = wave * 32;

    // staging source: lane l fetches (row = i*8 + (l>>3), kchunk = (l&7)^(l>>3))
    const size_t rowb = (size_t)K * 2;  // row stride bytes
    const char* sbase = (const char*)(wave ? (const void*)g.W : (const void*)g.A)
                      + (size_t)(wave ? n0 : m0) * rowb
                      + (size_t)(lane >> 3) * rowb
                      + (size_t)(((lane & 7) ^ (lane >> 3)) << 4);

    const int fr = lane & 15;
    const int fq = lane >> 4;           // 0..3

    f32x4 acc[2][4] = {};
    const int NT = K / 64;              // >= 4 assumed

    // prologue: issue tiles 0,1,2 into bufs 0,1,2 (24 loads/wave outstanding)
#pragma unroll
    for (int tt = 0; tt < 3; ++tt)
#pragma unroll
        for (int i = 0; i < 8; ++i)
            gload16(sbase + (size_t)tt * 128 + (size_t)i * 8 * rowb,
                    &lds[tt][wave][i * 512]);

#define GSTEP(VMW)                                                              \
    {                                                                           \
        asm volatile("s_waitcnt vmcnt(" #VMW ")" ::: "memory");                 \
        __builtin_amdgcn_s_barrier();        /* tile t resident, both halves */ \
        __builtin_amdgcn_sched_barrier(0);                                      \
        const int b = t % 3;                                                    \
        short8 af[2][2], wf[4][2];                                              \
        _Pragma("unroll")                                                       \
        for (int kk = 0; kk < 2; ++kk) {                                        \
            const int ch = kk * 4 + fq;                                         \
            _Pragma("unroll")                                                   \
            for (int i = 0; i < 2; ++i) {                                       \
                const int r = wm + i * 16 + fr;                                 \
                af[i][kk] = *(const short8*)&lds[b][0][r * 64 + ((ch ^ (r & 7)) << 3)]; \
            }                                                                   \
            _Pragma("unroll")                                                   \
            for (int j = 0; j < 4; ++j) {                                       \
                const int c = j * 16 + fr;                                      \
                wf[j][kk] = *(const short8*)&lds[b][1][c * 64 + ((ch ^ (c & 7)) << 3)]; \
            }                                                                   \
        }                                                                       \
        asm volatile("s_waitcnt lgkmcnt(0)" ::: "memory");                      \
        __builtin_amdgcn_sched_barrier(0);                                      \
        __builtin_amdgcn_s_barrier();        /* all reads of buf b done */      \
        if (t + 3 < NT) {                                                       \
            const char* p = sbase + (size_t)(t + 3) * 128;                      \
            _Pragma("unroll")                                                   \
            for (int i = 0; i < 8; ++i)                                         \
                gload16(p + (size_t)i * 8 * rowb, &lds[b][wave][i * 512]);      \
        }                                                                       \
        _Pragma("unroll")                                                       \
        for (int kk = 0; kk < 2; ++kk)                                          \
            _Pragma("unroll")                                                   \
            for (int i = 0; i < 2; ++i)                                         \
                _Pragma("unroll")                                               \
                for (int j = 0; j < 4; ++j)                                     \
                    acc[i][j] = __builtin_amdgcn_mfma_f32_16x16x32_bf16(        \
                        af[i][kk], wf[j][kk], acc[i][j], 0, 0, 0);              \
    }

    int t = 0;
    for (; t < NT - 2; ++t) GSTEP(16)   // tiles t+1,t+2 stay in flight
    GSTEP(8)                            // t = NT-2: only t+1 in flight
    ++t;
    GSTEP(0)                            // t = NT-1: drain
#undef GSTEP

    // epilogue: C/D layout col=lane&15, row=(lane>>4)*4+reg
#pragma unroll
    for (int i = 0; i < 2; ++i) {
        const int row0 = m0 + wm + i * 16 + fq * 4;
#pragma unroll
        for (int j = 0; j < 4; ++j) {
            const int col = n0 + j * 16 + fr;
            const float b = g.bias[col];
#pragma unroll
            for (int r = 0; r < 4; ++r) {
                float v = acc[i][j][r] + b;
                const size_t o = (size_t)(row0 + r) * NDIM + col;
                if (g.res) v += g.res[o];
                g.C[o] = v;
                if (g.Cb) g.Cb[o] = __float2bfloat16(v);
            }
        }
    }
}

// ---------------- sliding-window attention ----------------
struct AttnArgs {
    const float *Q, *K, *V, *kb, *vb;
    bf16* O;   // bf16 out -> feeds stage-4 GEMM A directly
};

// block = (32 query rows) x (1 head) x (1 attn); grid (16,8,2), 256 threads.
__global__ __launch_bounds__(256) void attn_tile(AttnArgs a0, AttnArgs a1) {
    const AttnArgs a = blockIdx.z ? a1 : a0;
    const int h  = blockIdx.y;
    const int n0 = blockIdx.x * 32;
    const int tid = threadIdx.x;

    __shared__ float Ks[97 * 128];
    __shared__ float Vs[97 * 128];
    __shared__ float Qs[32 * 132];
    __shared__ float Ps[32 * 68];
    __shared__ float InvS[32];

    // stage K/V window rows wp=0..96 (ctx rows n0-32 .. n0+64); OOB -> kb/vb
    for (int i = tid; i < 97 * 32; i += 256) {
        const int wp = i >> 5, d4 = i & 31;
        const int idx = n0 - 32 + wp;
        const bool valid = (idx >= 0) && (idx < MDIM);
        const float* sk = (valid ? (a.K + (size_t)idx * NDIM) : a.kb) + h * 128;
        const float* sv = (valid ? (a.V + (size_t)idx * NDIM) : a.vb) + h * 128;
        const float4 kv = *(const float4*)(sk + d4 * 4);
        const float4 vv = *(const float4*)(sv + d4 * 4);
        const int slot = d4 ^ (wp & 31);
        *(float4*)&Ks[wp * 128 + slot * 4] = kv;
        *(float4*)&Vs[wp * 128 + slot * 4] = vv;
    }
    for (int i = tid; i < 32 * 32; i += 256) {
        const int r = i >> 5, d4 = i & 31;
        *(float4*)&Qs[r * 132 + d4 * 4] =
            *(const float4*)(a.Q + (size_t)(n0 + r) * NDIM + h * 128 + d4 * 4);
    }
    __syncthreads();

    const int r = tid >> 3, sub = tid & 7;
    const int n = n0 + r;
    const int lo_inv = max(0, 32 - n);
    const int hi_inv = max(0, n - 478);
    const int n_zero = max(0, 64 - (LSLOT - lo_inv - hi_inv));
    const float scale = 0.088388347648318447f;  // 1/sqrt(128)

    float dots[9];
#pragma unroll
    for (int k = 0; k < 9; ++k) dots[k] = 0.f;
#pragma unroll
    for (int db = 0; db < 4; ++db) {
        float4 q[8];
#pragma unroll
        for (int c = 0; c < 8; ++c) q[c] = *(float4*)&Qs[r * 132 + (db * 8 + c) * 4];
        for (int k = 0; k < 9; ++k) {
            const int l = sub + 8 * k;
            if (l >= LSLOT) break;
            const int wp = r + l, key = wp & 31;
            float accd = dots[k];
#pragma unroll
            for (int c = 0; c < 8; ++c) {
                const int d4 = db * 8 + c;
                const float4 kv = *(float4*)&Ks[wp * 128 + (d4 ^ key) * 4];
                accd += kv.x * q[c].x + kv.y * q[c].y + kv.z * q[c].z + kv.w * q[c].w;
            }
            dots[k] = accd;
        }
    }
    for (int k = 0; k < 9; ++k) {
        const int l = sub + 8 * k;
        if (l >= LSLOT) break;
        const int idx = n - 32 + l;
        const bool valid = (idx >= 0) && (idx < MDIM);
        bool attend = valid;
        if (!valid) {
            const int ir = (l < lo_inv) ? l : (l - (LSLOT - hi_inv));
            attend = ir < n_zero;
        }
        Ps[r * 68 + l] = attend ? dots[k] * scale : -1e30f;
    }
    __syncthreads();

    {
        float m = -1e30f;
        for (int k = 0; k < 9; ++k) {
            const int l = sub + 8 * k;
            if (l < LSLOT) m = fmaxf(m, Ps[r * 68 + l]);
        }
        for (int s = 1; s < 8; s <<= 1) m = fmaxf(m, __shfl_xor(m, s, 64));
        float sum = 0.f;
        for (int k = 0; k < 9; ++k) {
            const int l = sub + 8 * k;
            if (l >= LSLOT) break;
            const float e = expf(Ps[r * 68 + l] - m);
            Ps[r * 68 + l] = e;
            sum += e;
        }
        for (int s = 1; s < 8; s <<= 1) sum += __shfl_xor(sum, s, 64);
        if (sub == 0) InvS[r] = 1.0f / sum;
    }
    __syncthreads();

    float4 acc[4] = {};
    for (int l = 0; l < LSLOT; ++l) {
        const float p = Ps[r * 68 + l];
        const int wp = r + l, key = wp & 31;
#pragma unroll
        for (int c = 0; c < 4; ++c) {
            const int d4 = sub + 8 * c;
            const float4 vv = *(float4*)&Vs[wp * 128 + (d4 ^ key) * 4];
            acc[c].x += p * vv.x; acc[c].y += p * vv.y;
            acc[c].z += p * vv.z; acc[c].w += p * vv.w;
        }
    }
    const float inv = InvS[r];
#pragma unroll
    for (int c = 0; c < 4; ++c) {
        short4v o;
        o[0] = f2bf(acc[c].x * inv); o[1] = f2bf(acc[c].y * inv);
        o[2] = f2bf(acc[c].z * inv); o[3] = f2bf(acc[c].w * inv);
        *(short4v*)((short*)a.O + (size_t)n * NDIM + h * 128 + (sub + 8 * c) * 4) = o;
    }
}

extern "C" void kernel_launch(void* const* d_in, const int* in_sizes, int n_in,
                              void* d_out, int out_size, void* d_ws, size_t ws_size,
                              hipStream_t stream) {
    const float* images = (const float*)d_in[0];   // (512,1024)
    const float* caps   = (const float*)d_in[1];   // (512,768)
    const float* tp_w = (const float*)d_in[3];
    const float* tp_b = (const float*)d_in[4];
    const float* ip_w = (const float*)d_in[5];
    const float* ip_b = (const float*)d_in[6];
    const float* ia_qw = (const float*)d_in[7];  const float* ia_qb = (const float*)d_in[8];
    const float* ia_kw = (const float*)d_in[9];  const float* ia_kb = (const float*)d_in[10];
    const float* ia_vw = (const float*)d_in[11]; const float* ia_vb = (const float*)d_in[12];
    const float* ia_ow = (const float*)d_in[13]; const float* ia_ob = (const float*)d_in[14];
    const float* ta_qw = (const float*)d_in[15]; const float* ta_qb = (const float*)d_in[16];
    const float* ta_kw = (const float*)d_in[17]; const float* ta_kb = (const float*)d_in[18];
    const float* ta_vw = (const float*)d_in[19]; const float* ta_vb = (const float*)d_in[20];
    const float* ta_ow = (const float*)d_in[21]; const float* ta_ob = (const float*)d_in[22];

    const size_t S = (size_t)MDIM * NDIM;          // 524288
    float* ws = (float*)d_ws;
    float* txt = ws + 0 * S;
    float* img = ws + 1 * S;
    float* Qi  = ws + 2 * S;
    float* Ki  = ws + 3 * S;
    float* Vi  = ws + 4 * S;
    float* Qt  = ws + 5 * S;
    float* Kt  = ws + 6 * S;
    float* Vt  = ws + 7 * S;
    bf16* bb     = (bf16*)(ws + 8 * S);
    bf16* capsb  = bb;               // 512*768
    bf16* imgsb  = capsb + 393216;   // 512*1024
    bf16* txtb   = imgsb + S;
    bf16* imgb   = txtb + S;
    bf16* Oib    = imgb + S;
    bf16* Otb    = Oib + S;
    bf16* tp_wb  = Otb + S;          // 1024*768
    bf16* ip_wb  = tp_wb + 786432;
    bf16* qwb[8];
    { bf16* p = ip_wb + 1048576;
      for (int i = 0; i < 8; ++i) { qwb[i] = p; p += 1048576; } }

    float* fused_img = (float*)d_out;
    float* fused_txt = (float*)d_out + S;

    // ---- prep: convert inputs + weights to bf16 ----
    CvtBatch cv = {};
    cv.d[0]  = {caps,   capsb, 393216};
    cv.d[1]  = {images, imgsb, (int)S};
    cv.d[2]  = {tp_w,   tp_wb, 786432};
    cv.d[3]  = {ip_w,   ip_wb, 1048576};
    cv.d[4]  = {ia_qw, qwb[0], 1048576};
    cv.d[5]  = {ia_kw, qwb[1], 1048576};
    cv.d[6]  = {ia_vw, qwb[2], 1048576};
    cv.d[7]  = {ia_ow, qwb[3], 1048576};
    cv.d[8]  = {ta_qw, qwb[4], 1048576};
    cv.d[9]  = {ta_kw, qwb[5], 1048576};
    cv.d[10] = {ta_vw, qwb[6], 1048576};
    cv.d[11] = {ta_ow, qwb[7], 1048576};
    cvt_bf16<<<dim3(512, 1, 12), 256, 0, stream>>>(cv);

    dim3 blk(128);
    dim3 tiles(NDIM / 64, MDIM / 64);  // 16 x 8

    // ---- stage 1: input projections (dual fp32 + bf16 out) ----
    GBatch b1 = {};
    b1.d[0] = {capsb, tp_wb, tp_b, nullptr, txt, txtb, 768};
    b1.d[1] = {imgsb, ip_wb, ip_b, nullptr, img, imgb, 1024};
    gemm_bf16<<<dim3(tiles.x, tiles.y, 2), blk, 0, stream>>>(b1);

    // ---- stage 2: QKV (fp32 out for attn) ----
    GBatch b2 = {};
    b2.d[0] = {imgb, qwb[0], ia_qb, nullptr, Qi, nullptr, 1024};
    b2.d[1] = {txtb, qwb[1], ia_kb, nullptr, Ki, nullptr, 1024};
    b2.d[2] = {txtb, qwb[2], ia_vb, nullptr, Vi, nullptr, 1024};
    b2.d[3] = {txtb, qwb[4], ta_qb, nullptr, Qt, nullptr, 1024};
    b2.d[4] = {imgb, qwb[5], ta_kb, nullptr, Kt, nullptr, 1024};
    b2.d[5] = {imgb, qwb[6], ta_vb, nullptr, Vt, nullptr, 1024};
    gemm_bf16<<<dim3(tiles.x, tiles.y, 6), blk, 0, stream>>>(b2);

    // ---- stage 3: attention (bf16 O out) ----
    AttnArgs aa = {Qi, Ki, Vi, ia_kb, ia_vb, Oib};
    AttnArgs ab = {Qt, Kt, Vt, ta_kb, ta_vb, Otb};
    attn_tile<<<dim3(16, 8, 2), 256, 0, stream>>>(aa, ab);

    // ---- stage 4: output projections + residual ----
    GBatch b4 = {};
    b4.d[0] = {Oib, qwb[3], ia_ob, img, fused_img, nullptr, 1024};
    b4.d[1] = {Otb, qwb[7], ta_ob, txt, fused_txt, nullptr, 1024};
    gemm_bf16<<<dim3(tiles.x, tiles.y, 2), blk, 0, stream>>>(b4);
}